// Round 6
// baseline (199.606 us; speedup 1.0000x reference)
//
#include <hip/hip_runtime.h>

// Grid: 512x512 nodes, idx = row*512 + col. h = 1/511.
// m_in = [s_dst, deg_dst, s_src, deg_src, ea_x, ea_y] @ W1 -> tanh -> @ W2
// g(s)[n] = (1/deg_n) * sum_incoming(msg) + b2
//
// R5: R4's forced-pk-f16 math, but hidden dim split 4-ways across lanes
// (4 lanes/node x 16 hidden units each, __shfl_xor reduce) to raise
// occupancy 4 waves/SIMD -> 8 and hide the tanh dependent-chain latency.
// Evidence: R3(2x instrs) ~= R4 time => not issue-bound; Occupancy was 28%.

#define GW    512
#define GN    (GW * GW)
#define HID   64
#define SPLIT 4
#define JPT   (HID / SPLIT)    // 16 hidden units per thread
#define NUC   0.01f

typedef _Float16 h2 __attribute__((ext_vector_type(2)));

__device__ __forceinline__ float h2f(h2 x) { return __builtin_bit_cast(float, x); }
__device__ __forceinline__ h2 f2h(float x) { return __builtin_bit_cast(h2, x); }

// Inline-asm packed f16 helpers (clang won't form v_pk_* from ext_vector on
// gfx950 — verified R3 vs R4). Operands proxied as 32-bit floats.
__device__ __forceinline__ h2 pk_fma(h2 a, h2 b, h2 c) {
    float d, fa = h2f(a), fb = h2f(b), fc = h2f(c);
    asm("v_pk_fma_f16 %0, %1, %2, %3" : "=v"(d) : "v"(fa), "v"(fb), "v"(fc));
    return f2h(d);
}
__device__ __forceinline__ h2 pk_mul(h2 a, h2 b) {
    float d, fa = h2f(a), fb = h2f(b);
    asm("v_pk_mul_f16 %0, %1, %2" : "=v"(d) : "v"(fa), "v"(fb));
    return f2h(d);
}
__device__ __forceinline__ h2 pk_add(h2 a, h2 b) {
    float d, fa = h2f(a), fb = h2f(b);
    asm("v_pk_add_f16 %0, %1, %2" : "=v"(d) : "v"(fa), "v"(fb));
    return f2h(d);
}
__device__ __forceinline__ h2 pk_min(h2 a, h2 b) {
    float d, fa = h2f(a), fb = h2f(b);
    asm("v_pk_min_f16 %0, %1, %2" : "=v"(d) : "v"(fa), "v"(fb));
    return f2h(d);
}
__device__ __forceinline__ h2 pk_max(h2 a, h2 b) {
    float d, fa = h2f(a), fb = h2f(b);
    asm("v_pk_max_f16 %0, %1, %2" : "=v"(d) : "v"(fa), "v"(fb));
    return f2h(d);
}

__device__ __forceinline__ h2 h2c(float x) {
    h2 r; r.x = (_Float16)x; r.y = (_Float16)x; return r;
}
__device__ __forceinline__ h2 h2p(float a, float b) {
    h2 r; r.x = (_Float16)a; r.y = (_Float16)b; return r;
}

struct TanhC { h2 c38, cm38, c105, c945, c15, c420, c2; };
__device__ __forceinline__ TanhC make_tc() {
    TanhC t;
    t.c38 = h2c(3.8f); t.cm38 = h2c(-3.8f); t.c105 = h2c(105.f);
    t.c945 = h2c(945.f); t.c15 = h2c(15.f); t.c420 = h2c(420.f); t.c2 = h2c(2.f);
    return t;
}

// tanh(t) ~= t(945+105s+s^2)/(945+420s+15s^2), s=t^2, t=clamp(x,+-3.8).
__device__ __forceinline__ h2 tanh_pk(h2 x, const TanhC& tc) {
    h2 t   = pk_min(tc.c38, pk_max(tc.cm38, x));
    h2 s   = pk_mul(t, t);
    h2 num = pk_mul(t, pk_fma(s, pk_add(s, tc.c105), tc.c945));
    h2 den = pk_fma(s, pk_fma(s, tc.c15, tc.c420), tc.c945);
    unsigned int db = __builtin_bit_cast(unsigned int, den);
    h2 r   = __builtin_bit_cast(h2, 0x77987798u - db);         // magic seed
    h2 nd  = __builtin_bit_cast(h2, db ^ 0x80008000u);         // -den
    r = pk_mul(r, pk_fma(nd, r, tc.c2));                       // Newton 1
    return pk_mul(num, r);
}

struct alignas(16) LWH {           // 32 B per hidden unit, broadcast pairs
    h2 a0, a1, a2, a3;             // W1 rows 0..3 (duplicated into both halves)
    h2 kLR, kUD;                   // b1 + ea.W1[4:6] folded per incoming dir
    h2 c0, c1;                     // W2 row (duplicated)
};

// Swizzled store: slot = jj*SPLIT + part for original j = part*JPT + jj, so a
// wave's 4 per-quad reads are CONSECUTIVE 32B structs -> conflict-free LDS.
__device__ __forceinline__ void fill_lds(LWH* lw, float* sb2,
                                         const float* __restrict__ W1,
                                         const float* __restrict__ b1,
                                         const float* __restrict__ W2,
                                         const float* __restrict__ b2) {
    const int t = threadIdx.x;
    if (t < HID) {
        const float H = 1.0f / 511.0f;
        float a4 = W1[4 * HID + t], a5 = W1[5 * HID + t];
        float b  = b1[t];
        LWH w;
        w.a0 = h2c(W1[0 * HID + t]); w.a1 = h2c(W1[1 * HID + t]);
        w.a2 = h2c(W1[2 * HID + t]); w.a3 = h2c(W1[3 * HID + t]);
        w.kLR = h2p(b - H * a4, b + H * a4);  // from left / from right
        w.kUD = h2p(b - H * a5, b + H * a5);  // from up / from down
        w.c0 = h2c(W2[2 * t + 0]);  w.c1 = h2c(W2[2 * t + 1]);
        const int slot = ((t & (JPT - 1)) * SPLIT) | (t / JPT);
        lw[slot] = w;
    }
    if (t < 2) sb2[t] = b2[t];
}

// Kernel 1: grad_u, grad_v, grad_p. SoA out: g[0]=gu0 g[1]=gu1 ... g[5]=gp1
__global__ void __launch_bounds__(256, 8) grad3_kernel(
    const float* __restrict__ fields, const float* __restrict__ degrees,
    const float* __restrict__ W1, const float* __restrict__ b1,
    const float* __restrict__ W2, const float* __restrict__ b2,
    float* __restrict__ g)
{
    __shared__ LWH lw[HID];
    __shared__ float sb2[2];
    fill_lds(lw, sb2, W1, b1, W2, b2);
    __syncthreads();

    const int gid  = blockIdx.x * 256 + threadIdx.x;
    const int idx  = gid >> 2;          // node (4 lanes per node)
    const int part = gid & 3;           // hidden-dim slice
    const int row = idx >> 9, col = idx & (GW - 1);
    const bool vE0 = col > 0, vE1 = col < GW - 1, vE2 = row > 0, vE3 = row < GW - 1;
    int nb[4];
    nb[0] = vE0 ? idx - 1  : idx;
    nb[1] = vE1 ? idx + 1  : idx;
    nb[2] = vE2 ? idx - GW : idx;
    nb[3] = vE3 ? idx + GW : idx;

    const TanhC tc = make_tc();

    h2 s0h[3];
    #pragma unroll
    for (int f = 0; f < 3; ++f) s0h[f] = h2c(fields[3 * idx + f]);
    h2 sN2[2][3];                       // [pair LR/UD][field]
    #pragma unroll
    for (int f = 0; f < 3; ++f) {
        sN2[0][f] = h2p(fields[3 * nb[0] + f], fields[3 * nb[1] + f]);
        sN2[1][f] = h2p(fields[3 * nb[2] + f], fields[3 * nb[3] + f]);
    }
    h2 dnbLR = h2p(degrees[nb[0]], degrees[nb[1]]);
    h2 dnbUD = h2p(degrees[nb[2]], degrees[nb[3]]);
    const float dN = degrees[idx];
    const h2 dNh = h2c(dN);

    h2 acc[2][3][2];                    // [pair][field][W2 comp]
    #pragma unroll
    for (int dp = 0; dp < 2; ++dp)
        #pragma unroll
        for (int f = 0; f < 3; ++f) { acc[dp][f][0] = h2c(0.f); acc[dp][f][1] = h2c(0.f); }

    const LWH* lwp = lw + part;         // quad-consecutive slots
    #pragma unroll 2
    for (int jj = 0; jj < JPT; ++jj) {
        LWH w = lwp[jj * SPLIT];
        h2 dn1 = pk_mul(dNh, w.a1);
        h2 hb[2];
        hb[0] = pk_fma(dnbLR, w.a3, pk_add(w.kLR, dn1));
        hb[1] = pk_fma(dnbUD, w.a3, pk_add(w.kUD, dn1));
        #pragma unroll
        for (int f = 0; f < 3; ++f) {
            #pragma unroll
            for (int dp = 0; dp < 2; ++dp) {
                h2 hh = pk_fma(sN2[dp][f], w.a2, pk_fma(s0h[f], w.a0, hb[dp]));
                h2 th = tanh_pk(hh, tc);
                acc[dp][f][0] = pk_fma(th, w.c0, acc[dp][f][0]);
                acc[dp][f][1] = pk_fma(th, w.c1, acc[dp][f][1]);
            }
        }
    }

    const float rd = __builtin_amdgcn_rcpf(dN);
    #pragma unroll
    for (int f = 0; f < 3; ++f) {
        #pragma unroll
        for (int c = 0; c < 2; ++c) {
            float s = 0.f;
            s += vE0 ? (float)acc[0][f][c].x : 0.f;
            s += vE1 ? (float)acc[0][f][c].y : 0.f;
            s += vE2 ? (float)acc[1][f][c].x : 0.f;
            s += vE3 ? (float)acc[1][f][c].y : 0.f;
            s += __shfl_xor(s, 1);
            s += __shfl_xor(s, 2);
            if (part == 0)
                g[(2 * f + c) * GN + idx] = __builtin_fmaf(s, rd, sb2[c]);
        }
    }
}

// Kernel 2: second-order g on gu0,gu1,gv0,gv1 (needed comps 0,1,0,1) + combine.
__global__ void __launch_bounds__(256, 8) final_kernel(
    const float* __restrict__ fields, const float* __restrict__ degrees,
    const float* __restrict__ W1, const float* __restrict__ b1,
    const float* __restrict__ W2, const float* __restrict__ b2,
    const float* __restrict__ g, float* __restrict__ out)
{
    __shared__ LWH lw[HID];
    __shared__ float sb2[2];
    fill_lds(lw, sb2, W1, b1, W2, b2);
    __syncthreads();

    const int gid  = blockIdx.x * 256 + threadIdx.x;
    const int idx  = gid >> 2;
    const int part = gid & 3;
    const int row = idx >> 9, col = idx & (GW - 1);
    const bool vE0 = col > 0, vE1 = col < GW - 1, vE2 = row > 0, vE3 = row < GW - 1;
    int nb[4];
    nb[0] = vE0 ? idx - 1  : idx;
    nb[1] = vE1 ? idx + 1  : idx;
    nb[2] = vE2 ? idx - GW : idx;
    nb[3] = vE3 ? idx + GW : idx;

    const TanhC tc = make_tc();

    float s0[4];
    #pragma unroll
    for (int f = 0; f < 4; ++f) s0[f] = g[f * GN + idx];
    h2 s0h[4];
    #pragma unroll
    for (int f = 0; f < 4; ++f) s0h[f] = h2c(s0[f]);
    h2 sN2[2][4];
    #pragma unroll
    for (int f = 0; f < 4; ++f) {
        sN2[0][f] = h2p(g[f * GN + nb[0]], g[f * GN + nb[1]]);
        sN2[1][f] = h2p(g[f * GN + nb[2]], g[f * GN + nb[3]]);
    }
    h2 dnbLR = h2p(degrees[nb[0]], degrees[nb[1]]);
    h2 dnbUD = h2p(degrees[nb[2]], degrees[nb[3]]);
    const float dN = degrees[idx];
    const h2 dNh = h2c(dN);

    h2 acc[2][4];                       // [pair][field]
    #pragma unroll
    for (int dp = 0; dp < 2; ++dp)
        #pragma unroll
        for (int f = 0; f < 4; ++f) acc[dp][f] = h2c(0.f);

    const LWH* lwp = lw + part;
    #pragma unroll 2
    for (int jj = 0; jj < JPT; ++jj) {
        LWH w = lwp[jj * SPLIT];
        h2 dn1 = pk_mul(dNh, w.a1);
        h2 hb[2];
        hb[0] = pk_fma(dnbLR, w.a3, pk_add(w.kLR, dn1));
        hb[1] = pk_fma(dnbUD, w.a3, pk_add(w.kUD, dn1));
        #pragma unroll
        for (int f = 0; f < 4; ++f) {
            h2 cc = (f & 1) ? w.c1 : w.c0;   // needed comp: 0,1,0,1
            #pragma unroll
            for (int dp = 0; dp < 2; ++dp) {
                h2 hh = pk_fma(sN2[dp][f], w.a2, pk_fma(s0h[f], w.a0, hb[dp]));
                h2 th = tanh_pk(hh, tc);
                acc[dp][f] = pk_fma(th, cc, acc[dp][f]);
            }
        }
    }

    const float rd = __builtin_amdgcn_rcpf(dN);
    float r[4];
    #pragma unroll
    for (int f = 0; f < 4; ++f) {
        float s = 0.f;
        s += vE0 ? (float)acc[0][f].x : 0.f;
        s += vE1 ? (float)acc[0][f].y : 0.f;
        s += vE2 ? (float)acc[1][f].x : 0.f;
        s += vE3 ? (float)acc[1][f].y : 0.f;
        s += __shfl_xor(s, 1);
        s += __shfl_xor(s, 2);
        r[f] = __builtin_fmaf(s, rd, sb2[f & 1]);
    }

    if (part == 0) {
        const float lap_u = r[0] + r[1];
        const float lap_v = r[2] + r[3];
        const float u = fields[3 * idx + 0], v = fields[3 * idx + 1];
        const float gu0 = s0[0], gu1 = s0[1], gv0 = s0[2], gv1 = s0[3];
        const float gp0 = g[4 * GN + idx], gp1 = g[5 * GN + idx];
        out[3 * idx + 0] = gu0 + gv1;
        out[3 * idx + 1] = u * gu0 + v * gu1 + gp0 - NUC * lap_u;
        out[3 * idx + 2] = u * gv0 + v * gv1 + gp1 - NUC * lap_v;
    }
}

extern "C" void kernel_launch(void* const* d_in, const int* in_sizes, int n_in,
                              void* d_out, int out_size, void* d_ws, size_t ws_size,
                              hipStream_t stream) {
    const float* fields  = (const float*)d_in[0];
    const float* degrees = (const float*)d_in[1];
    const float* W1 = (const float*)d_in[3];
    const float* b1 = (const float*)d_in[4];
    const float* W2 = (const float*)d_in[5];
    const float* b2 = (const float*)d_in[6];
    float* g   = (float*)d_ws;           // 6 * GN floats = 6.3 MB scratch
    float* out = (float*)d_out;

    const int blocks = (GN * SPLIT) / 256;   // 4096
    grad3_kernel<<<blocks, 256, 0, stream>>>(fields, degrees, W1, b1, W2, b2, g);
    final_kernel<<<blocks, 256, 0, stream>>>(fields, degrees, W1, b1, W2, b2, g, out);
}